// Round 9
// baseline (3070.329 us; speedup 1.0000x reference)
//
#include <hip/hip_runtime.h>

#define DIN 512
#define H   1024
#define NBATCH 64
#define SEQ 512
#define M_TOTAL (NBATCH * SEQ)  // 32768

typedef float  f32x4  __attribute__((ext_vector_type(4)));
typedef __bf16 bf16x8 __attribute__((ext_vector_type(8)));
typedef short  s16x8  __attribute__((ext_vector_type(8)));
typedef short  s16x4  __attribute__((ext_vector_type(4)));

__device__ __forceinline__ unsigned short f2bf(float f) {
  unsigned u = __float_as_uint(f);
  u = (u + 0x7FFFu + ((u >> 16) & 1u)) >> 16;   // RNE truncate to bf16
  return (unsigned short)u;
}
__device__ __forceinline__ float bf2f(unsigned short h) {
  return __uint_as_float(((unsigned)h) << 16);
}
__device__ __forceinline__ f32x4 mfma_bf16(s16x8 a, s16x8 b, f32x4 c) {
  return __builtin_amdgcn_mfma_f32_16x16x32_bf16(
      __builtin_bit_cast(bf16x8, a), __builtin_bit_cast(bf16x8, b), c, 0, 0, 0);
}
// coherent (sc1) accesses: served at the die-level coherence point,
// no cache-maintenance side effects (proven R2/R4/R5/R8)
__device__ __forceinline__ s16x8 ld_sc1_b128(const short* p) {
  s16x8 r;
  asm volatile("global_load_dwordx4 %0, %1, off sc1"
               : "=v"(r) : "v"(p) : "memory");
  return r;
}
__device__ __forceinline__ void st_sc1_b128(short* p, s16x8 v) {
  asm volatile("global_store_dwordx4 %0, %1, off sc1"
               :: "v"(p), "v"(v) : "memory");
}

// ---------------- prep: transpose + hi/lo bf16 convert --------------------
__global__ void conv_T(const float* __restrict__ in, int R, int C,
                       short* __restrict__ oh, short* __restrict__ ol) {
  int i = blockIdx.x * 256 + threadIdx.x;
  if (i >= R * C) return;
  int c = i / R, r = i - c * R;
  float v = in[r * C + c];
  unsigned short hb = f2bf(v);
  oh[i] = (short)hb;
  ol[i] = (short)f2bf(v - bf2f(hb));
}

// broadcast h0[1][H] into h-buffer slot 1 (read by scan step t=0)
__global__ void init_h(const float* __restrict__ h0,
                       short* __restrict__ h_hi, short* __restrict__ h_lo) {
  int i = blockIdx.x * 256 + threadIdx.x;      // 64*1024
  int c = i & (H - 1);
  float v = h0[c];
  unsigned short hb = f2bf(v);
  h_hi[NBATCH * H + i] = (short)hb;            // slot 1
  h_lo[NBATCH * H + i] = (short)f2bf(v - bf2f(hb));
}

// ---------------- projection GEMM: xp = x @ w_xh + b_xh + b_hh ------------
#define PBM 64
#define PBN 128
#define PBK 64
__global__ __launch_bounds__(256) void proj_kernel(
    const float* __restrict__ x,       // [M][DIN]
    const short* __restrict__ wT_hi,   // [H][DIN]
    const short* __restrict__ wT_lo,
    const float* __restrict__ b_xh,
    const float* __restrict__ b_hh,
    float* __restrict__ out) {         // [M][H] (d_out hidden region)
  __shared__ short Ahi[PBM * PBK], Alo[PBM * PBK];
  __shared__ short Bhi[PBN * PBK], Blo[PBN * PBK];
  const int n0 = blockIdx.x * PBN;
  const int m0 = blockIdx.y * PBM;
  const int tid = threadIdx.x;
  const int lane = tid & 63, w = tid >> 6;
  const int wr = w >> 1, wc = w & 1;
  const int l15 = lane & 15, kq8 = (lane >> 4) << 3;

  f32x4 acc[2][4];
#pragma unroll
  for (int a = 0; a < 2; ++a)
#pragma unroll
    for (int b = 0; b < 4; ++b) acc[a][b] = (f32x4){0.f, 0.f, 0.f, 0.f};

  for (int kc = 0; kc < DIN; kc += PBK) {
    {
      int r = tid >> 2, k0 = (tid & 3) << 4;
      const float* src = x + (size_t)(m0 + r) * DIN + kc + k0;
#pragma unroll
      for (int i = 0; i < 4; ++i) {
        float4 v = *(const float4*)(src + i * 4);
        unsigned short h0b = f2bf(v.x), h1b = f2bf(v.y), h2b = f2bf(v.z), h3b = f2bf(v.w);
        s16x4 hv = {(short)h0b, (short)h1b, (short)h2b, (short)h3b};
        s16x4 lv = {(short)f2bf(v.x - bf2f(h0b)), (short)f2bf(v.y - bf2f(h1b)),
                    (short)f2bf(v.z - bf2f(h2b)), (short)f2bf(v.w - bf2f(h3b))};
        int ad = (r * PBK + k0 + i * 4) * 2;
        ad ^= (r & 7) << 4;
        *(s16x4*)((char*)Ahi + ad) = hv;
        *(s16x4*)((char*)Alo + ad) = lv;
      }
    }
    {
      int c = tid >> 1, k0 = (tid & 1) << 5;
      const short* sh = wT_hi + (size_t)(n0 + c) * DIN + kc + k0;
      const short* sl = wT_lo + (size_t)(n0 + c) * DIN + kc + k0;
#pragma unroll
      for (int i = 0; i < 4; ++i) {
        s16x8 vh = *(const s16x8*)(sh + i * 8);
        s16x8 vl = *(const s16x8*)(sl + i * 8);
        int ad = (c * PBK + k0 + i * 8) * 2;
        ad ^= (c & 7) << 4;
        *(s16x8*)((char*)Bhi + ad) = vh;
        *(s16x8*)((char*)Blo + ad) = vl;
      }
    }
    __syncthreads();
#pragma unroll
    for (int ks = 0; ks < PBK; ks += 32) {
      s16x8 ah[2], al[2], bh[4], bl[4];
#pragma unroll
      for (int rt = 0; rt < 2; ++rt) {
        int row = wr * 32 + rt * 16 + l15;
        int ad = (row * PBK + ks + kq8) * 2;
        ad ^= (row & 7) << 4;
        ah[rt] = *(const s16x8*)((const char*)Ahi + ad);
        al[rt] = *(const s16x8*)((const char*)Alo + ad);
      }
#pragma unroll
      for (int ct = 0; ct < 4; ++ct) {
        int c = wc * 64 + ct * 16 + l15;
        int ad = (c * PBK + ks + kq8) * 2;
        ad ^= (c & 7) << 4;
        bh[ct] = *(const s16x8*)((const char*)Bhi + ad);
        bl[ct] = *(const s16x8*)((const char*)Blo + ad);
      }
#pragma unroll
      for (int rt = 0; rt < 2; ++rt)
#pragma unroll
        for (int ct = 0; ct < 4; ++ct) {
          acc[rt][ct] = mfma_bf16(ah[rt], bh[ct], acc[rt][ct]);
          acc[rt][ct] = mfma_bf16(al[rt], bh[ct], acc[rt][ct]);
          acc[rt][ct] = mfma_bf16(ah[rt], bl[ct], acc[rt][ct]);
        }
    }
    __syncthreads();
  }
#pragma unroll
  for (int rt = 0; rt < 2; ++rt)
#pragma unroll
    for (int ct = 0; ct < 4; ++ct) {
      int col = n0 + wc * 64 + ct * 16 + l15;
      float bias = b_xh[col] + b_hh[col];
#pragma unroll
      for (int i = 0; i < 4; ++i) {
        int m = m0 + wr * 32 + rt * 16 + ((lane >> 4) << 2) + i;
        out[(size_t)m * H + col] = acc[rt][ct][i] + bias;
      }
    }
}

// ---------------- persistent recurrent scan (v9) ---------------------------
// R8 skeleton with a slimmed release leg:
//  * PER-WAVE flags (64 per (bg,t)): each wave drains ONLY its own packed
//    h-store (the single vmem op since the staging drain) then flags.
//    No pre-flag __syncthreads.
//  * out[] stores + xp(t+1) prefetch DEFERRED until after the flag — they
//    are block-private and complete under the next poll/stage (waited by the
//    next staging vmcnt(0)).
//  * LDS h-tile double-buffered by parity (WAR safety without end barrier;
//    per-iteration staging barrier bounds wave skew).
__global__ __launch_bounds__(256, 1) void scan_kernel(
    const short* __restrict__ whT_hi,  // [H][H]
    const short* __restrict__ whT_lo,
    float* __restrict__ out,           // d_out: [64][512][1024] then [64][1024]
    short* __restrict__ h_hi,          // [2][64][1024]
    short* __restrict__ h_lo,
    int* __restrict__ flags) {         // [4][512][64]
  __shared__ short Hh[2][16 * H];      // 64 KB double-buffered (hi)
  __shared__ short Hl[2][16 * H];      // 64 KB (lo)
  __shared__ unsigned TR[4][16][20];   // 5 KB per-wave transpose scratch
  const int tid = threadIdx.x;
  const int lane = tid & 63, w = tid >> 6;
  const int bid = blockIdx.x;
  const int bg = bid & 3, cg4 = bid >> 2;
  const int l15 = lane & 15, kq = lane >> 4, kq8 = kq << 3;
  const int colbase = cg4 * 64 + w * 16;
  const int col = colbase + l15;
  const int rowbase = bg * 16;
  const int NB = NBATCH * H;

  // W hi+lo fragments in registers/AGPRs: 64 x s16x8
  s16x8 whi[32], wlo[32];
#pragma unroll
  for (int kk = 0; kk < 32; ++kk) {
    whi[kk] = *(const s16x8*)(whT_hi + (size_t)col * H + kk * 32 + kq8);
    wlo[kk] = *(const s16x8*)(whT_lo + (size_t)col * H + kk * 32 + kq8);
  }

  // per-thread staging chunk offsets (constant across steps)
  int cbase[8];
#pragma unroll
  for (int j = 0; j < 8; ++j) {
    int c = j * 256 + tid;
    cbase[j] = (rowbase + (c >> 7)) * H + ((c & 127) << 3);
  }

  // xp prefetch for t=0 (no poll at t=0, off the critical path)
  float xp[4]; unsigned offs[4];
#pragma unroll
  for (int i = 0; i < 4; ++i) {
    int b = rowbase + kq * 4 + i;
    offs[i] = ((unsigned)b * SEQ + 0) * H + col;
    xp[i] = out[offs[i]];
  }

  for (int t = 0; t < SEQ; ++t) {
    const int prev = (t + 1) & 1, cur = t & 1;

    // ---- poll per-wave flags for step t-1 (64 flags, one per lane) ----
    if (t > 0) {
      const int* f = flags + ((bg * SEQ + (t - 1)) << 6);
      int spins = 0;
      while (true) {
        int v = __hip_atomic_load(f + lane, __ATOMIC_RELAXED, __HIP_MEMORY_SCOPE_AGENT);
        if (__all(v != 0)) break;
        if (++spins > 20000) break;  // safety: wrong answer beats a hang
        __builtin_amdgcn_s_sleep(1);
      }
      __builtin_amdgcn_sched_barrier(0);
    }

    // ---- bulk stage h(t-1) -> LDS buf[t&1] (16 b128 sc1 loads in flight) --
    {
      const short* ghi = h_hi + (size_t)prev * NB;
      const short* glo = h_lo + (size_t)prev * NB;
      s16x8 sh[8], sl[8];
#pragma unroll
      for (int j = 0; j < 8; ++j) {
        sh[j] = ld_sc1_b128(ghi + cbase[j]);
        sl[j] = ld_sc1_b128(glo + cbase[j]);
      }
      asm volatile("s_waitcnt vmcnt(0)" ::: "memory");
      __builtin_amdgcn_sched_barrier(0);
      char* HB = (char*)&Hh[cur][0];
      char* LB = (char*)&Hl[cur][0];
#pragma unroll
      for (int j = 0; j < 8; ++j) {
        int c = j * 256 + tid;
        int ad = (c << 4) ^ (((c >> 7) & 7) << 4);   // XOR-swizzled
        *(s16x8*)(HB + ad) = sh[j];
        *(s16x8*)(LB + ad) = sl[j];
      }
    }
    __syncthreads();

    // ---- compute: 96 MFMA over the staged tile ----
    f32x4 acc[2][3];
#pragma unroll
    for (int a = 0; a < 2; ++a)
#pragma unroll
      for (int b = 0; b < 3; ++b) acc[a][b] = (f32x4){0.f, 0.f, 0.f, 0.f};
    const char* HB = (const char*)&Hh[cur][0];
    const char* LB = (const char*)&Hl[cur][0];
#pragma unroll
    for (int kk = 0; kk < 32; ++kk) {
      int ad = ((l15 * H + kk * 32 + kq8) * 2) ^ ((l15 & 7) << 4);
      s16x8 a_hi = *(const s16x8*)(HB + ad);
      s16x8 a_lo = *(const s16x8*)(LB + ad);
      int p = kk & 1;
      acc[p][0] = mfma_bf16(a_hi, whi[kk], acc[p][0]);
      acc[p][1] = mfma_bf16(a_lo, whi[kk], acc[p][1]);
      acc[p][2] = mfma_bf16(a_hi, wlo[kk], acc[p][2]);
    }
    f32x4 s = acc[0][0] + acc[0][1] + acc[0][2] + acc[1][0] + acc[1][1] + acc[1][2];

    // ---- tanh + per-wave transpose + ONE packed b128 h-store per lane ----
    float val[4];
    unsigned short hbv[4], lbv[4];
#pragma unroll
    for (int i = 0; i < 4; ++i) {
      float pre = s[i] + xp[i];
      float e = __expf(2.f * pre);
      val[i] = 1.f - 2.f / (e + 1.f);                  // tanh
      hbv[i] = f2bf(val[i]);
      lbv[i] = f2bf(val[i] - bf2f(hbv[i]));
    }
    unsigned* tr = &TR[w][0][0];
#pragma unroll
    for (int i = 0; i < 4; ++i)
      tr[(kq * 4 + i) * 20 + l15] = (unsigned)hbv[i] | ((unsigned)lbv[i] << 16);
    asm volatile("s_waitcnt lgkmcnt(0)" ::: "memory");
    __builtin_amdgcn_sched_barrier(0);
    {
      int rrow = lane & 15, rhalf = (lane >> 4) & 1;
      const unsigned* src = &tr[rrow * 20 + rhalf * 8];
      uint4 wa = *(const uint4*)(src);
      uint4 wb = *(const uint4*)(src + 4);
      unsigned o0, o1, o2, o3;
      if (lane < 32) {          // hi plane: low halves
        o0 = (wa.x & 0xFFFFu) | (wa.y << 16);
        o1 = (wa.z & 0xFFFFu) | (wa.w << 16);
        o2 = (wb.x & 0xFFFFu) | (wb.y << 16);
        o3 = (wb.z & 0xFFFFu) | (wb.w << 16);
      } else {                  // lo plane: high halves
        o0 = (wa.x >> 16) | (wa.y & 0xFFFF0000u);
        o1 = (wa.z >> 16) | (wa.w & 0xFFFF0000u);
        o2 = (wb.x >> 16) | (wb.y & 0xFFFF0000u);
        o3 = (wb.z >> 16) | (wb.w & 0xFFFF0000u);
      }
      uint4 pk4 = {o0, o1, o2, o3};
      short* plane = (lane < 32) ? h_hi : h_lo;
      short* dst = plane + (size_t)cur * NB
                 + (size_t)(rowbase + rrow) * H + colbase + rhalf * 8;
      st_sc1_b128(dst, __builtin_bit_cast(s16x8, pk4));
    }
    // ---- release: drain ONLY the h-store, then this wave's flag ----
    asm volatile("s_waitcnt vmcnt(0)" ::: "memory");
    if (lane == 0)
      __hip_atomic_store(&flags[((bg * SEQ + t) << 6) + cg4 * 4 + w], 1,
                         __ATOMIC_RELAXED, __HIP_MEMORY_SCOPE_AGENT);
    __builtin_amdgcn_sched_barrier(0);

    // ---- deferred (block-private; hidden under next poll/stage) ----
#pragma unroll
    for (int i = 0; i < 4; ++i) {
      out[offs[i]] = val[i];
      if (t == SEQ - 1)
        out[(size_t)M_TOTAL * H + (size_t)(rowbase + kq * 4 + i) * H + col] = val[i];
    }
    if (t + 1 < SEQ) {
#pragma unroll
      for (int i = 0; i < 4; ++i) {
        int b = rowbase + kq * 4 + i;
        unsigned o = ((unsigned)b * SEQ + (t + 1)) * H + col;
        xp[i] = out[o];
        offs[i] = o;
      }
    }
  }
}

// ---------------- launch ---------------------------------------------------
extern "C" void kernel_launch(void* const* d_in, const int* in_sizes, int n_in,
                              void* d_out, int out_size, void* d_ws, size_t ws_size,
                              hipStream_t stream) {
  const float* x    = (const float*)d_in[0];
  const float* w_xh = (const float*)d_in[1];
  const float* b_xh = (const float*)d_in[2];
  const float* w_hh = (const float*)d_in[3];
  const float* b_hh = (const float*)d_in[4];
  const float* h0   = (const float*)d_in[5];
  float* out = (float*)d_out;
  char* ws = (char*)d_ws;

  short* wxT_hi = (short*)(ws + 0);            // 1,048,576
  short* wxT_lo = (short*)(ws + 1048576);      // 1,048,576
  short* whT_hi = (short*)(ws + 2097152);      // 2,097,152
  short* whT_lo = (short*)(ws + 4194304);      // 2,097,152
  short* h_hi   = (short*)(ws + 6291456);      // 2*64*1024*2 = 262,144
  short* h_lo   = (short*)(ws + 6553600);      // 262,144
  int*   flags  = (int*)  (ws + 6815744);      // 4*512*64*4 = 524,288
  // total 7,340,032 bytes

  hipMemsetAsync(ws + 6815744, 0, 524288, stream);  // reset sync flags each call

  conv_T<<<(DIN * H + 255) / 256, 256, 0, stream>>>(w_xh, DIN, H, wxT_hi, wxT_lo);
  conv_T<<<(H * H + 255) / 256, 256, 0, stream>>>(w_hh, H, H, whT_hi, whT_lo);
  init_h<<<(NBATCH * H) / 256, 256, 0, stream>>>(h0, h_hi, h_lo);

  proj_kernel<<<dim3(H / PBN, M_TOTAL / PBM), 256, 0, stream>>>(
      x, wxT_hi, wxT_lo, b_xh, b_hh, out);

  scan_kernel<<<64, 256, 0, stream>>>(whT_hi, whT_lo, out, h_hi, h_lo, flags);
}

// Round 10
// 2343.615 us; speedup vs baseline: 1.3101x; 1.3101x over previous
//
#include <hip/hip_runtime.h>

#define DIN 512
#define H   1024
#define NBATCH 64
#define SEQ 512
#define M_TOTAL (NBATCH * SEQ)  // 32768

typedef float  f32x4  __attribute__((ext_vector_type(4)));
typedef __bf16 bf16x8 __attribute__((ext_vector_type(8)));
typedef short  s16x8  __attribute__((ext_vector_type(8)));
typedef short  s16x4  __attribute__((ext_vector_type(4)));

__device__ __forceinline__ unsigned short f2bf(float f) {
  unsigned u = __float_as_uint(f);
  u = (u + 0x7FFFu + ((u >> 16) & 1u)) >> 16;   // RNE truncate to bf16
  return (unsigned short)u;
}
__device__ __forceinline__ float bf2f(unsigned short h) {
  return __uint_as_float(((unsigned)h) << 16);
}
__device__ __forceinline__ f32x4 mfma_bf16(s16x8 a, s16x8 b, f32x4 c) {
  return __builtin_amdgcn_mfma_f32_16x16x32_bf16(
      __builtin_bit_cast(bf16x8, a), __builtin_bit_cast(bf16x8, b), c, 0, 0, 0);
}
// coherent (sc1) bulk load: pipelines freely, serves at the coherence point
__device__ __forceinline__ s16x8 ld_sc1_b128(const short* p) {
  s16x8 r;
  asm volatile("global_load_dwordx4 %0, %1, off sc1"
               : "=v"(r) : "v"(p) : "memory");
  return r;
}
__device__ __forceinline__ void st_agent16(unsigned short* p, unsigned short v) {
  __hip_atomic_store(p, v, __ATOMIC_RELAXED, __HIP_MEMORY_SCOPE_AGENT);
}

// ---------------- prep: transpose + hi/lo bf16 convert --------------------
__global__ void conv_T(const float* __restrict__ in, int R, int C,
                       short* __restrict__ oh, short* __restrict__ ol) {
  int i = blockIdx.x * 256 + threadIdx.x;
  if (i >= R * C) return;
  int c = i / R, r = i - c * R;
  float v = in[r * C + c];
  unsigned short hb = f2bf(v);
  oh[i] = (short)hb;
  ol[i] = (short)f2bf(v - bf2f(hb));
}

// broadcast h0[1][H] into h-buffer slot 1 (read by scan step t=0)
__global__ void init_h(const float* __restrict__ h0,
                       short* __restrict__ h_hi, short* __restrict__ h_lo) {
  int i = blockIdx.x * 256 + threadIdx.x;      // 64*1024
  int c = i & (H - 1);
  float v = h0[c];
  unsigned short hb = f2bf(v);
  h_hi[NBATCH * H + i] = (short)hb;            // slot 1
  h_lo[NBATCH * H + i] = (short)f2bf(v - bf2f(hb));
}

// ---------------- projection GEMM: xp = x @ w_xh + b_xh + b_hh ------------
#define PBM 64
#define PBN 128
#define PBK 64
__global__ __launch_bounds__(256) void proj_kernel(
    const float* __restrict__ x,       // [M][DIN]
    const short* __restrict__ wT_hi,   // [H][DIN]
    const short* __restrict__ wT_lo,
    const float* __restrict__ b_xh,
    const float* __restrict__ b_hh,
    float* __restrict__ out) {         // [M][H] (d_out hidden region)
  __shared__ short Ahi[PBM * PBK], Alo[PBM * PBK];
  __shared__ short Bhi[PBN * PBK], Blo[PBN * PBK];
  const int n0 = blockIdx.x * PBN;
  const int m0 = blockIdx.y * PBM;
  const int tid = threadIdx.x;
  const int lane = tid & 63, w = tid >> 6;
  const int wr = w >> 1, wc = w & 1;
  const int l15 = lane & 15, kq8 = (lane >> 4) << 3;

  f32x4 acc[2][4];
#pragma unroll
  for (int a = 0; a < 2; ++a)
#pragma unroll
    for (int b = 0; b < 4; ++b) acc[a][b] = (f32x4){0.f, 0.f, 0.f, 0.f};

  for (int kc = 0; kc < DIN; kc += PBK) {
    {
      int r = tid >> 2, k0 = (tid & 3) << 4;
      const float* src = x + (size_t)(m0 + r) * DIN + kc + k0;
#pragma unroll
      for (int i = 0; i < 4; ++i) {
        float4 v = *(const float4*)(src + i * 4);
        unsigned short h0b = f2bf(v.x), h1b = f2bf(v.y), h2b = f2bf(v.z), h3b = f2bf(v.w);
        s16x4 hv = {(short)h0b, (short)h1b, (short)h2b, (short)h3b};
        s16x4 lv = {(short)f2bf(v.x - bf2f(h0b)), (short)f2bf(v.y - bf2f(h1b)),
                    (short)f2bf(v.z - bf2f(h2b)), (short)f2bf(v.w - bf2f(h3b))};
        int ad = (r * PBK + k0 + i * 4) * 2;
        ad ^= (r & 7) << 4;
        *(s16x4*)((char*)Ahi + ad) = hv;
        *(s16x4*)((char*)Alo + ad) = lv;
      }
    }
    {
      int c = tid >> 1, k0 = (tid & 1) << 5;
      const short* sh = wT_hi + (size_t)(n0 + c) * DIN + kc + k0;
      const short* sl = wT_lo + (size_t)(n0 + c) * DIN + kc + k0;
#pragma unroll
      for (int i = 0; i < 4; ++i) {
        s16x8 vh = *(const s16x8*)(sh + i * 8);
        s16x8 vl = *(const s16x8*)(sl + i * 8);
        int ad = (c * PBK + k0 + i * 8) * 2;
        ad ^= (c & 7) << 4;
        *(s16x8*)((char*)Bhi + ad) = vh;
        *(s16x8*)((char*)Blo + ad) = vl;
      }
    }
    __syncthreads();
#pragma unroll
    for (int ks = 0; ks < PBK; ks += 32) {
      s16x8 ah[2], al[2], bh[4], bl[4];
#pragma unroll
      for (int rt = 0; rt < 2; ++rt) {
        int row = wr * 32 + rt * 16 + l15;
        int ad = (row * PBK + ks + kq8) * 2;
        ad ^= (row & 7) << 4;
        ah[rt] = *(const s16x8*)((const char*)Ahi + ad);
        al[rt] = *(const s16x8*)((const char*)Alo + ad);
      }
#pragma unroll
      for (int ct = 0; ct < 4; ++ct) {
        int c = wc * 64 + ct * 16 + l15;
        int ad = (c * PBK + ks + kq8) * 2;
        ad ^= (c & 7) << 4;
        bh[ct] = *(const s16x8*)((const char*)Bhi + ad);
        bl[ct] = *(const s16x8*)((const char*)Blo + ad);
      }
#pragma unroll
      for (int rt = 0; rt < 2; ++rt)
#pragma unroll
        for (int ct = 0; ct < 4; ++ct) {
          acc[rt][ct] = mfma_bf16(ah[rt], bh[ct], acc[rt][ct]);
          acc[rt][ct] = mfma_bf16(al[rt], bh[ct], acc[rt][ct]);
          acc[rt][ct] = mfma_bf16(ah[rt], bl[ct], acc[rt][ct]);
        }
    }
    __syncthreads();
  }
#pragma unroll
  for (int rt = 0; rt < 2; ++rt)
#pragma unroll
    for (int ct = 0; ct < 4; ++ct) {
      int col = n0 + wc * 64 + ct * 16 + l15;
      float bias = b_xh[col] + b_hh[col];
#pragma unroll
      for (int i = 0; i < 4; ++i) {
        int m = m0 + wr * 32 + rt * 16 + ((lane >> 4) << 2) + i;
        out[(size_t)m * H + col] = acc[rt][ct][i] + bias;
      }
    }
}

// ---------------- persistent recurrent scan (R4 verbatim — measured 2204us)
// 64 blocks x 256 threads (4 waves). bg = bid&3 (16 batch rows), cg4 = bid>>2
// (64 cols; wave w owns 16). W_hi AND W_lo fragments in registers (256 regs).
// Per step: xp prefetch (hidden under poll) -> poll 16 block-flags ->
// cooperative bulk sc1 load of h[16x1024] hi+lo -> LDS (XOR-swz) -> barrier
// -> 96 MFMA -> tanh -> out stores (fast L2 ack) + 8 scalar sc1 h-stores ->
// vmcnt(0) drain -> barrier -> 1 flag/block.
__global__ __launch_bounds__(256, 1) void scan_kernel(
    const short* __restrict__ whT_hi,  // [H][H]
    const short* __restrict__ whT_lo,
    float* __restrict__ out,           // d_out: [64][512][1024] then [64][1024]
    short* __restrict__ h_hi,          // [2][64][1024]
    short* __restrict__ h_lo,
    int* __restrict__ flags) {         // [4][512][16]
  __shared__ short Hhi[16 * H];        // 32 KB, XOR-swizzled rows
  __shared__ short Hlo[16 * H];        // 32 KB
  const int tid = threadIdx.x;
  const int lane = tid & 63, w = tid >> 6;
  const int bid = blockIdx.x;
  const int bg = bid & 3, cg4 = bid >> 2;
  const int l15 = lane & 15, kq = lane >> 4, kq8 = kq << 3;
  const int col = cg4 * 64 + w * 16 + l15;
  const int rowbase = bg * 16;

  // preload W hi+lo fragments into registers: 2 x 32 x s16x8 = 256 regs
  s16x8 whi[32], wlo[32];
#pragma unroll
  for (int kk = 0; kk < 32; ++kk) {
    whi[kk] = *(const s16x8*)(whT_hi + (size_t)col * H + kk * 32 + kq8);
    wlo[kk] = *(const s16x8*)(whT_lo + (size_t)col * H + kk * 32 + kq8);
  }

  for (int t = 0; t < SEQ; ++t) {
    const int prev = (t + 1) & 1, cur = t & 1;

    // prefetch this step's xp (independent of h / flags; hidden under poll)
    float xp[4];
    unsigned offs[4];
#pragma unroll
    for (int i = 0; i < 4; ++i) {
      int b = rowbase + kq * 4 + i;
      offs[i] = ((unsigned)b * SEQ + t) * H + col;
      xp[i] = out[offs[i]];
    }

    if (t > 0) {
      const int* f = flags + ((bg * SEQ + (t - 1)) << 4);
      int spins = 0;
      while (true) {
        int v = 1;
        if (lane < 16)
          v = __hip_atomic_load(f + lane, __ATOMIC_RELAXED, __HIP_MEMORY_SCOPE_AGENT);
        if (__all(v != 0)) break;
        if (++spins > 20000) break;  // safety: wrong answer beats a hang
        __builtin_amdgcn_s_sleep(1);
      }
      __builtin_amdgcn_sched_barrier(0);
    }

    // cooperative bulk stage: h[16][1024] hi+lo -> LDS, all loads in flight.
    // chunk c = j*256 + tid (lane-contiguous 16B chunks per instruction);
    // 8 chunks hi + 8 chunks lo per thread = full 2048-chunk tile per buffer.
    {
      const short* ghi = h_hi + (size_t)prev * NBATCH * H;
      const short* glo = h_lo + (size_t)prev * NBATCH * H;
      s16x8 sh[8], sl[8];
#pragma unroll
      for (int j = 0; j < 8; ++j) {
        int c = j * 256 + tid;
        int r = c >> 7;                        // 0..15 within tile
        int k0 = (c & 127) << 3;               // short offset within row
        sh[j] = ld_sc1_b128(ghi + (rowbase + r) * H + k0);
        sl[j] = ld_sc1_b128(glo + (rowbase + r) * H + k0);
      }
      asm volatile("s_waitcnt vmcnt(0)" ::: "memory");
      __builtin_amdgcn_sched_barrier(0);
#pragma unroll
      for (int j = 0; j < 8; ++j) {
        int c = j * 256 + tid;
        int r = c >> 7;
        int ad = (c << 4) ^ ((r & 7) << 4);    // byte addr, XOR-swizzled
        *(s16x8*)((char*)Hhi + ad) = sh[j];
        *(s16x8*)((char*)Hlo + ad) = sl[j];
      }
    }
    __syncthreads();

    f32x4 acc[2][3];
#pragma unroll
    for (int a = 0; a < 2; ++a)
#pragma unroll
      for (int b = 0; b < 3; ++b) acc[a][b] = (f32x4){0.f, 0.f, 0.f, 0.f};

#pragma unroll
    for (int kk = 0; kk < 32; ++kk) {
      int ad = (l15 * H + kk * 32 + kq8) * 2;
      ad ^= (l15 & 7) << 4;
      s16x8 a_hi = *(const s16x8*)((const char*)Hhi + ad);
      s16x8 a_lo = *(const s16x8*)((const char*)Hlo + ad);
      int p = kk & 1;
      acc[p][0] = mfma_bf16(a_hi, whi[kk], acc[p][0]);
      acc[p][1] = mfma_bf16(a_lo, whi[kk], acc[p][1]);
      acc[p][2] = mfma_bf16(a_hi, wlo[kk], acc[p][2]);
    }
    f32x4 s = acc[0][0] + acc[0][1] + acc[0][2] + acc[1][0] + acc[1][1] + acc[1][2];

#pragma unroll
    for (int i = 0; i < 4; ++i) {
      int b = rowbase + kq * 4 + i;                       // C row -> batch
      float pre = s[i] + xp[i];
      float e = __expf(2.f * pre);
      float val = 1.f - 2.f / (e + 1.f);                  // tanh
      out[offs[i]] = val;
      unsigned short hb = f2bf(val);
      unsigned short lb = f2bf(val - bf2f(hb));
      st_agent16((unsigned short*)&h_hi[(size_t)(cur * NBATCH + b) * H + col], hb);
      st_agent16((unsigned short*)&h_lo[(size_t)(cur * NBATCH + b) * H + col], lb);
      if (t == SEQ - 1)
        out[(size_t)M_TOTAL * H + (size_t)b * H + col] = val;
    }
    // release: drain this wave's sc1 stores, then block-wide barrier, 1 flag
    asm volatile("s_waitcnt vmcnt(0)" ::: "memory");
    __syncthreads();
    if (tid == 0)
      __hip_atomic_store(&flags[((bg * SEQ + t) << 4) + cg4], 1,
                         __ATOMIC_RELAXED, __HIP_MEMORY_SCOPE_AGENT);
  }
}

// ---------------- launch ---------------------------------------------------
extern "C" void kernel_launch(void* const* d_in, const int* in_sizes, int n_in,
                              void* d_out, int out_size, void* d_ws, size_t ws_size,
                              hipStream_t stream) {
  const float* x    = (const float*)d_in[0];
  const float* w_xh = (const float*)d_in[1];
  const float* b_xh = (const float*)d_in[2];
  const float* w_hh = (const float*)d_in[3];
  const float* b_hh = (const float*)d_in[4];
  const float* h0   = (const float*)d_in[5];
  float* out = (float*)d_out;
  char* ws = (char*)d_ws;

  short* wxT_hi = (short*)(ws + 0);            // 1,048,576
  short* wxT_lo = (short*)(ws + 1048576);      // 1,048,576
  short* whT_hi = (short*)(ws + 2097152);      // 2,097,152
  short* whT_lo = (short*)(ws + 4194304);      // 2,097,152
  short* h_hi   = (short*)(ws + 6291456);      // 262,144
  short* h_lo   = (short*)(ws + 6553600);      // 262,144
  int*   flags  = (int*)  (ws + 6815744);      // 4*512*16*4 = 131,072
  // total 6,946,816 bytes

  hipMemsetAsync(ws + 6815744, 0, 131072, stream);  // reset sync flags each call

  conv_T<<<(DIN * H + 255) / 256, 256, 0, stream>>>(w_xh, DIN, H, wxT_hi, wxT_lo);
  conv_T<<<(H * H + 255) / 256, 256, 0, stream>>>(w_hh, H, H, whT_hi, whT_lo);
  init_h<<<(NBATCH * H) / 256, 256, 0, stream>>>(h0, h_hi, h_lo);

  proj_kernel<<<dim3(H / PBN, M_TOTAL / PBM), 256, 0, stream>>>(
      x, wxT_hi, wxT_lo, b_xh, b_hh, out);

  scan_kernel<<<64, 256, 0, stream>>>(whT_hi, whT_lo, out, h_hi, h_lo, flags);
}